// Round 2
// baseline (2074.716 us; speedup 1.0000x reference)
//
#include <hip/hip_runtime.h>
#include <math.h>

// Simple_RNN: B=256, T=1000, D=128 (feat) + 128 (mask), L=128, H=64
// Persistent recurrent kernel: 1 batch row per block (256 blocks = 256 CUs),
// 512 threads, all weights in registers, activations in LDS, lgkm-only barriers.

#define TT 1000

// Raw barrier: order LDS ops only (do NOT drain vmcnt -> data prefetch survives).
__device__ __forceinline__ void barx() {
  __builtin_amdgcn_sched_barrier(0);
  asm volatile("s_waitcnt lgkmcnt(0)" ::: "memory");
  __builtin_amdgcn_s_barrier();
  __builtin_amdgcn_sched_barrier(0);
}

__device__ __forceinline__ float fast_tanh(float x) {
  // overflow-safe: operate on |x|, exp(-2a) <= 1
  float a = fabsf(x);
  float t = __expf(-2.0f * a);
  float r = (1.0f - t) / (1.0f + t);
  return copysignf(r, x);
}
__device__ __forceinline__ float fast_sig(float x) {
  return 1.0f / (1.0f + __expf(-x));  // x->-inf: exp=inf -> 0; x->+inf: -> 1
}

extern "C" __global__ void __launch_bounds__(512, 2)
rnn_fused(const float* __restrict__ data, const float* __restrict__ ts,
          const float* __restrict__ uw1, const float* __restrict__ ub1,
          const float* __restrict__ uw2, const float* __restrict__ ub2,
          const float* __restrict__ rw1, const float* __restrict__ rb1,
          const float* __restrict__ rw2, const float* __restrict__ rb2,
          const float* __restrict__ nw1, const float* __restrict__ nb1,
          const float* __restrict__ nw2, const float* __restrict__ nb2,
          float* __restrict__ out) {
  constexpr int YCS = 36;  // padded stride per 32-elem chunk (144B: 16B-aligned, bank-rotating)
  constexpr int HS  = 20;  // padded stride per 16-elem chunk (80B)
  const int tid = threadIdx.x;
  const int b   = blockIdx.x;

  __shared__ __align__(16) float yc[8 * YCS];   // k=kc*32+j -> yc[kc*YCS+j]; y: kc 0-3, xf: kc 4-7
  __shared__ __align__(16) float ccy[4 * YCS];  // y*r part of cc
  __shared__ __align__(16) float Hu[4 * HS];
  __shared__ __align__(16) float Hr[4 * HS];
  __shared__ __align__(16) float Hn[4 * HS];
  __shared__ float Ub[128];
  __shared__ float mflag;

  // ---- time_intervals output (independent; folded in here) ----
  {
    const float* tsb = ts + b * TT;
    float* oi = out + 32768000 + b * (TT - 1);
    for (int i = tid; i < TT - 1; i += 512) oi[i] = tsb[i + 1] - tsb[i];
  }

  // ---- thread roles ----
  const int h1  = tid >> 3, kc1 = tid & 7;  // stage1: 64 h x 8 k-chunks (k=kc1*32..+32 of 256)
  const int n2  = tid >> 2, hc2 = tid & 3;  // stage2: 128 n x 4 h-chunks (h=hc2*16..+16 of 64)

  // ---- weights in registers (one-time, L2-served) ----
  float w1u[32], w1r[32], w1n[32];
  #pragma unroll
  for (int j = 0; j < 32; ++j) {
    const int k = kc1 * 32 + j;
    w1u[j] = uw1[k * 64 + h1];
    w1r[j] = rw1[k * 64 + h1];
    w1n[j] = nw1[k * 64 + h1];
  }
  float w2u[16], w2r[16], w2n[16];
  #pragma unroll
  for (int j = 0; j < 16; ++j) {
    const int h = hc2 * 16 + j;
    w2u[j] = uw2[h * 128 + n2];
    w2r[j] = rw2[h * 128 + n2];
    w2n[j] = nw2[h * 128 + n2];
  }
  const float b1u = ub1[h1], b1r = rb1[h1], b1n = nb1[h1];
  const float b2u = ub2[n2], b2r = rb2[n2], b2n = nb2[n2];

  const float* db = data + (size_t)b * TT * 256;

  // ---- prologue: y0 = 0, stage xf_0 (128 floats = 32 thr x float4), mask_0 ----
  if (tid < 128) yc[(tid >> 5) * YCS + (tid & 31)] = 0.0f;
  if (tid < 32) {
    const int e = 4 * tid;                       // e in [0,128)
    float4 v = *(const float4*)(db + e);
    *(float4*)&yc[(4 + (e >> 5)) * YCS + (e & 31)] = v;
  }
  if (tid >= 64 && tid < 96) {  // lanes 0-31 of wave 1: mask elems 128..255
    const int e = 4 * (tid - 64);                // e in [0,128)
    float4 v = *(const float4*)(db + 128 + e);
    unsigned long long bal = __ballot((v.x + v.y + v.z + v.w) > 0.0f);
    if (tid == 64) mflag = (bal != 0ULL) ? 1.0f : 0.0f;
  }
  barx();

  float* lat = out + 32768;  // latent_ys base

  #pragma unroll 1
  for (int t = 0; t < TT; ++t) {
    // phase 1: issue next-step data loads (consumed after last barrier; vmcnt wait lands there)
    const bool have = (t + 1 < TT);
    float4 pf, pm;
    if (have && tid < 32)
      pf = *(const float4*)(db + (size_t)(t + 1) * 256 + 4 * tid);
    if (have && tid >= 64 && tid < 96)
      pm = *(const float4*)(db + (size_t)(t + 1) * 256 + 128 + 4 * (tid - 64));

    // phase 2: stage1 u,r  (hu/hr partial over this thread's 32-k slice)
    float au = 0.0f, ar = 0.0f;
    #pragma unroll
    for (int j4 = 0; j4 < 8; ++j4) {
      const float4 yv = *(const float4*)&yc[kc1 * YCS + 4 * j4];
      au = fmaf(yv.x, w1u[4*j4+0], au); ar = fmaf(yv.x, w1r[4*j4+0], ar);
      au = fmaf(yv.y, w1u[4*j4+1], au); ar = fmaf(yv.y, w1r[4*j4+1], ar);
      au = fmaf(yv.z, w1u[4*j4+2], au); ar = fmaf(yv.z, w1r[4*j4+2], ar);
      au = fmaf(yv.w, w1u[4*j4+3], au); ar = fmaf(yv.w, w1r[4*j4+3], ar);
    }
    au += __shfl_xor(au, 1); au += __shfl_xor(au, 2); au += __shfl_xor(au, 4);
    ar += __shfl_xor(ar, 1); ar += __shfl_xor(ar, 2); ar += __shfl_xor(ar, 4);
    if (kc1 == 0) {
      Hu[(h1 >> 4) * HS + (h1 & 15)] = fast_tanh(au + b1u);
      Hr[(h1 >> 4) * HS + (h1 & 15)] = fast_tanh(ar + b1r);
    }
    barx();

    // phase 4: stage2 u,r -> U, and cc_y = y * r (fused into r writer)
    float su = 0.0f, sr = 0.0f;
    #pragma unroll
    for (int j4 = 0; j4 < 4; ++j4) {
      const float4 hu = *(const float4*)&Hu[hc2 * HS + 4 * j4];
      const float4 hr = *(const float4*)&Hr[hc2 * HS + 4 * j4];
      su = fmaf(hu.x, w2u[4*j4+0], su); sr = fmaf(hr.x, w2r[4*j4+0], sr);
      su = fmaf(hu.y, w2u[4*j4+1], su); sr = fmaf(hr.y, w2r[4*j4+1], sr);
      su = fmaf(hu.z, w2u[4*j4+2], su); sr = fmaf(hr.z, w2r[4*j4+2], sr);
      su = fmaf(hu.w, w2u[4*j4+3], su); sr = fmaf(hr.w, w2r[4*j4+3], sr);
    }
    su += __shfl_xor(su, 1); su += __shfl_xor(su, 2);
    sr += __shfl_xor(sr, 1); sr += __shfl_xor(sr, 2);
    if (hc2 == 0) {
      Ub[n2] = fast_sig(su + b2u);
      const float rv = fast_sig(sr + b2r);
      ccy[(n2 >> 5) * YCS + (n2 & 31)] = rv * yc[(n2 >> 5) * YCS + (n2 & 31)];
    }
    barx();

    // phase 6: stage1 n (k<128 from cc_y, k>=128 from xf slots of yc)
    float an = 0.0f;
    const float* src = (kc1 < 4) ? &ccy[kc1 * YCS] : &yc[kc1 * YCS];
    #pragma unroll
    for (int j4 = 0; j4 < 8; ++j4) {
      const float4 v = *(const float4*)(src + 4 * j4);
      an = fmaf(v.x, w1n[4*j4+0], an);
      an = fmaf(v.y, w1n[4*j4+1], an);
      an = fmaf(v.z, w1n[4*j4+2], an);
      an = fmaf(v.w, w1n[4*j4+3], an);
    }
    an += __shfl_xor(an, 1); an += __shfl_xor(an, 2); an += __shfl_xor(an, 4);
    if (kc1 == 0) Hn[(h1 >> 4) * HS + (h1 & 15)] = fast_tanh(an + b1n);
    barx();

    // phase 8: stage2 n + blend + store
    float sn = 0.0f;
    #pragma unroll
    for (int j4 = 0; j4 < 4; ++j4) {
      const float4 hn = *(const float4*)&Hn[hc2 * HS + 4 * j4];
      sn = fmaf(hn.x, w2n[4*j4+0], sn);
      sn = fmaf(hn.y, w2n[4*j4+1], sn);
      sn = fmaf(hn.z, w2n[4*j4+2], sn);
      sn = fmaf(hn.w, w2n[4*j4+3], sn);
    }
    sn += __shfl_xor(sn, 1); sn += __shfl_xor(sn, 2);
    if (hc2 == 0) {
      const float ns   = sn + b2n;
      const float yold = yc[(n2 >> 5) * YCS + (n2 & 31)];
      const float uv   = Ub[n2];
      // (1-u)*ns + u*yold = ns + u*(yold-ns); masked rows keep yold
      const float ny = (mflag > 0.5f) ? fmaf(uv, yold - ns, ns) : yold;
      yc[(n2 >> 5) * YCS + (n2 & 31)] = ny;
      if (t < TT - 1) lat[((size_t)b * (TT - 1) + t) * 128 + n2] = ny;
      else            out[b * 128 + n2] = ny;
    }
    barx();

    // phase 10: install prefetched xf_{t+1} / mask_{t+1}
    if (have) {
      if (tid < 32) {
        const int e = 4 * tid;
        *(float4*)&yc[(4 + (e >> 5)) * YCS + (e & 31)] = pf;
      }
      if (tid >= 64 && tid < 96) {
        unsigned long long bal = __ballot((pm.x + pm.y + pm.z + pm.w) > 0.0f);
        if (tid == 64) mflag = (bal != 0ULL) ? 1.0f : 0.0f;
      }
      barx();
    }
  }
}

extern "C" void kernel_launch(void* const* d_in, const int* in_sizes, int n_in,
                              void* d_out, int out_size, void* d_ws, size_t ws_size,
                              hipStream_t stream) {
  const float* data = (const float*)d_in[0];
  const float* ts   = (const float*)d_in[1];
  const float* uw1  = (const float*)d_in[2];
  const float* ub1  = (const float*)d_in[3];
  const float* uw2  = (const float*)d_in[4];
  const float* ub2  = (const float*)d_in[5];
  const float* rw1  = (const float*)d_in[6];
  const float* rb1  = (const float*)d_in[7];
  const float* rw2  = (const float*)d_in[8];
  const float* rb2  = (const float*)d_in[9];
  const float* nw1  = (const float*)d_in[10];
  const float* nb1  = (const float*)d_in[11];
  const float* nw2  = (const float*)d_in[12];
  const float* nb2  = (const float*)d_in[13];

  rnn_fused<<<dim3(256), dim3(512), 0, stream>>>(
      data, ts, uw1, ub1, uw2, ub2, rw1, rb1, rw2, rb2, nw1, nb1, nw2, nb2,
      (float*)d_out);
}

// Round 3
// 1561.797 us; speedup vs baseline: 1.3284x; 1.3284x over previous
//
#include <hip/hip_runtime.h>
#include <math.h>

// Simple_RNN: B=256, T=1000, D=128(feat)+128(mask), L=128, H=64
// Persistent kernel: 1 row/block, 256 blocks, 512 threads.
// f16x2-packed weights in VGPRs (pinned), v_dot2_f32_f16, DPP quad reductions,
// 4 lgkm-only barriers/step, xf install overlapped with P4.

#define TT 1000

typedef _Float16 h2 __attribute__((ext_vector_type(2)));

#if defined(__has_builtin)
#if __has_builtin(__builtin_amdgcn_fdot2)
#define HAVE_FDOT2 1
#endif
#endif

__device__ __forceinline__ float dot2(unsigned int a, unsigned int b, float c) {
  h2 x = __builtin_bit_cast(h2, a);
  h2 y = __builtin_bit_cast(h2, b);
#ifdef HAVE_FDOT2
  return __builtin_amdgcn_fdot2(x, y, c, false);
#else
  return fmaf((float)x[1], (float)y[1], fmaf((float)x[0], (float)y[0], c));
#endif
}

__device__ __forceinline__ unsigned int packw(float a, float b) {
  h2 v; v[0] = (_Float16)a; v[1] = (_Float16)b;
  return __builtin_bit_cast(unsigned int, v);
}

// quad_perm DPP butterfly adds (groups of 4 lanes; VALU-speed, no LDS pipe)
__device__ __forceinline__ float dpp_add_xor1(float x) {
  int o = __builtin_amdgcn_update_dpp(0, __float_as_int(x), 0xB1, 0xF, 0xF, true);
  return x + __int_as_float(o);
}
__device__ __forceinline__ float dpp_add_xor2(float x) {
  int o = __builtin_amdgcn_update_dpp(0, __float_as_int(x), 0x4E, 0xF, 0xF, true);
  return x + __int_as_float(o);
}

// Barrier ordering LDS only (keeps prefetch loads in flight across it).
__device__ __forceinline__ void barx() {
  __builtin_amdgcn_sched_barrier(0);
  asm volatile("s_waitcnt lgkmcnt(0)" ::: "memory");
  __builtin_amdgcn_s_barrier();
  __builtin_amdgcn_sched_barrier(0);
}

__device__ __forceinline__ float fast_tanh(float x) {
  float a = fabsf(x);
  float t = __expf(-2.0f * a);
  float r = (1.0f - t) / (1.0f + t);
  return copysignf(r, x);
}
__device__ __forceinline__ float fast_sig(float x) {
  return 1.0f / (1.0f + __expf(-x));
}

extern "C" __global__ void __launch_bounds__(512, 2)
rnn_fused(const float* __restrict__ data, const float* __restrict__ ts,
          const float* __restrict__ uw1, const float* __restrict__ ub1,
          const float* __restrict__ uw2, const float* __restrict__ ub2,
          const float* __restrict__ rw1, const float* __restrict__ rb1,
          const float* __restrict__ rw2, const float* __restrict__ rb2,
          const float* __restrict__ nw1, const float* __restrict__ nb1,
          const float* __restrict__ nw2, const float* __restrict__ nb2,
          float* __restrict__ out) {
  const int tid = threadIdx.x;
  const int b   = blockIdx.x;

  // packed f16x2 LDS (uint words). ycpk: halves 0..127 = y, 128..255 = xf.
  __shared__ __align__(16) unsigned int ycpk[128];
  __shared__ __align__(16) unsigned int ccpk[64];   // halves 0..127 = y*r
  __shared__ __align__(16) unsigned int Hu[32], Hr[32], Hn[32];
  __shared__ float yf32[128];
  __shared__ float Ub[128];
  __shared__ float mflag[2];

  // ---- time_intervals ----
  {
    const float* tsb = ts + b * TT;
    float* oi = out + 32768000 + b * (TT - 1);
    for (int i = tid; i < TT - 1; i += 512) oi[i] = tsb[i + 1] - tsb[i];
  }

  // ---- roles ----
  // P1: job=tid>>2 (128): g=tid>>8 (0:u,1:r), h=(tid>>2)&63, ks=tid&3 (64-elem k-slice)
  // P2: job=tid>>1 (256): g=tid>>8, n=(tid>>1)&127, hs=tid&1 (32-elem h-slice)
  // P3 (tid<256): h=(tid>>2)&63, ks=tid&3 over cc
  // P4 (tid<256): n=tid>>1, hs=tid&1 ; tid>=256: xf install + mask ballot
  const int g  = tid >> 8;
  const int h1 = (tid >> 2) & 63, ks1 = tid & 3;
  const int n2 = (tid >> 1) & 127, hs2 = tid & 1;

  // ---- packed weights in registers (one-time) ----
  unsigned int w1[32], w2[16], w3[32], w4[16];
  {
    const float* W = g ? rw1 : uw1;
    #pragma unroll
    for (int j = 0; j < 32; ++j) {
      const int k = ks1 * 64 + 2 * j;
      w1[j] = packw(W[k * 64 + h1], W[(k + 1) * 64 + h1]);
    }
  }
  {
    const float* W = g ? rw2 : uw2;
    #pragma unroll
    for (int j = 0; j < 16; ++j) {
      const int hh = hs2 * 32 + 2 * j;
      w2[j] = packw(W[hh * 128 + n2], W[(hh + 1) * 128 + n2]);
    }
  }
  #pragma unroll
  for (int j = 0; j < 32; ++j) {
    const int k = ks1 * 64 + 2 * j;
    w3[j] = packw(nw1[k * 64 + h1], nw1[(k + 1) * 64 + h1]);
  }
  #pragma unroll
  for (int j = 0; j < 16; ++j) {
    const int hh = hs2 * 32 + 2 * j;
    w4[j] = packw(nw2[hh * 128 + n2], nw2[(hh + 1) * 128 + n2]);
  }
  const float b1 = (g ? rb1 : ub1)[h1];
  const float b2 = (g ? rb2 : ub2)[n2];
  const float b3 = nb1[h1];
  const float b4 = nb2[n2];

  const float* db = data + (size_t)b * TT * 256;

  // ---- prologue: y0=0, xf_0, mask_0 ----
  if (tid < 128) yf32[tid] = 0.0f;
  if (tid < 64)  ycpk[tid] = 0u;           // y halves = 0
  if (tid < 32) {
    const int e = 4 * tid;                 // feature elems [0,128)
    float4 v = *(const float4*)(db + e);
    ycpk[64 + (e >> 1)]     = packw(v.x, v.y);
    ycpk[64 + (e >> 1) + 1] = packw(v.z, v.w);
  }
  if (tid >= 64 && tid < 96) {             // lanes 0..31 of wave 1: mask elems
    const int e = 4 * (tid - 64);
    float4 v = *(const float4*)(db + 128 + e);
    unsigned long long bal = __ballot((v.x + v.y + v.z + v.w) > 0.0f);
    if (tid == 64) mflag[0] = (bal != 0ULL) ? 1.0f : 0.0f;
  }
  barx();

  float* lat = out + 32768;

  #pragma unroll 1
  for (int t = 0; t < TT; ++t) {
    // pin packed weights: compiler must keep them live in VGPRs (no remat/reload)
    #pragma unroll
    for (int j = 0; j < 32; ++j) asm volatile("" : "+v"(w1[j]));
    #pragma unroll
    for (int j = 0; j < 16; ++j) asm volatile("" : "+v"(w2[j]));
    #pragma unroll
    for (int j = 0; j < 32; ++j) asm volatile("" : "+v"(w3[j]));
    #pragma unroll
    for (int j = 0; j < 16; ++j) asm volatile("" : "+v"(w4[j]));

    const bool have = (t + 1 < TT);
    float4 pf, pm;
    if (have && tid >= 256 && tid < 288)
      pf = *(const float4*)(db + (size_t)(t + 1) * 256 + 4 * (tid - 256));
    if (have && tid >= 320 && tid < 352)
      pm = *(const float4*)(db + (size_t)(t + 1) * 256 + 128 + 4 * (tid - 320));

    // ---- P1: stage1 u,r : 256-elem dots, 4-thread slices ----
    {
      float a0 = 0.f, a1 = 0.f, a2 = 0.f, a3 = 0.f;
      const unsigned int* yb = &ycpk[ks1 * 32];
      #pragma unroll
      for (int r = 0; r < 8; ++r) {
        uint4 x = *(const uint4*)(yb + 4 * r);
        a0 = dot2(x.x, w1[4 * r + 0], a0);
        a1 = dot2(x.y, w1[4 * r + 1], a1);
        a2 = dot2(x.z, w1[4 * r + 2], a2);
        a3 = dot2(x.w, w1[4 * r + 3], a3);
      }
      float v = (a0 + a1) + (a2 + a3);
      v = dpp_add_xor1(v);
      v = dpp_add_xor2(v);
      if (ks1 == 0) {
        float hv = fast_tanh(v + b1);
        ((_Float16*)(g ? Hr : Hu))[h1] = (_Float16)hv;
      }
    }
    barx();

    // ---- P2: stage2 u,r : 64-elem dots, 2-thread slices; Ub / ccy ----
    {
      float c0 = 0.f, c1 = 0.f;
      const unsigned int* hb = (g ? Hr : Hu) + hs2 * 16;
      #pragma unroll
      for (int r = 0; r < 4; ++r) {
        uint4 x = *(const uint4*)(hb + 4 * r);
        c0 = dot2(x.x, w2[4 * r + 0], c0);
        c1 = dot2(x.y, w2[4 * r + 1], c1);
        c0 = dot2(x.z, w2[4 * r + 2], c0);
        c1 = dot2(x.w, w2[4 * r + 3], c1);
      }
      float s = c0 + c1;
      s = dpp_add_xor1(s);
      if (hs2 == 0) {
        float sg = fast_sig(s + b2);
        if (g) ((_Float16*)ccpk)[n2] = (_Float16)(sg * yf32[n2]);  // r: y*r
        else   Ub[n2] = sg;                                        // u
      }
    }
    barx();

    // ---- P3: stage1 n over cc=[y*r, xf] ----
    if (tid < 256) {
      float a0 = 0.f, a1 = 0.f, a2 = 0.f, a3 = 0.f;
      const unsigned int* sb = (ks1 < 2) ? &ccpk[ks1 * 32] : &ycpk[64 + (ks1 - 2) * 32];
      #pragma unroll
      for (int r = 0; r < 8; ++r) {
        uint4 x = *(const uint4*)(sb + 4 * r);
        a0 = dot2(x.x, w3[4 * r + 0], a0);
        a1 = dot2(x.y, w3[4 * r + 1], a1);
        a2 = dot2(x.z, w3[4 * r + 2], a2);
        a3 = dot2(x.w, w3[4 * r + 3], a3);
      }
      float v = (a0 + a1) + (a2 + a3);
      v = dpp_add_xor1(v);
      v = dpp_add_xor2(v);
      if (ks1 == 0) ((_Float16*)Hn)[h1] = (_Float16)fast_tanh(v + b3);
    }
    barx();

    // ---- P4: stage2 n + blend + store | install xf_{t+1} ----
    if (tid < 256) {
      float c0 = 0.f, c1 = 0.f;
      const unsigned int* hb = Hn + hs2 * 16;
      #pragma unroll
      for (int r = 0; r < 4; ++r) {
        uint4 x = *(const uint4*)(hb + 4 * r);
        c0 = dot2(x.x, w4[4 * r + 0], c0);
        c1 = dot2(x.y, w4[4 * r + 1], c1);
        c0 = dot2(x.z, w4[4 * r + 2], c0);
        c1 = dot2(x.w, w4[4 * r + 3], c1);
      }
      float s = c0 + c1;
      s = dpp_add_xor1(s);
      if (hs2 == 0) {
        const int nn = tid >> 1;
        const float ns   = s + b4;
        const float yold = yf32[nn];
        const float uv   = Ub[nn];
        const float ny = (mflag[t & 1] > 0.5f) ? fmaf(uv, yold - ns, ns) : yold;
        yf32[nn] = ny;
        ((_Float16*)ycpk)[nn] = (_Float16)ny;
        if (t < TT - 1) lat[((size_t)b * (TT - 1) + t) * 128 + nn] = ny;
        else            out[b * 128 + nn] = ny;
      }
    } else if (have) {
      if (tid < 288) {
        const int e = 4 * (tid - 256);
        ycpk[64 + (e >> 1)]     = packw(pf.x, pf.y);
        ycpk[64 + (e >> 1) + 1] = packw(pf.z, pf.w);
      }
      if (tid >= 320 && tid < 352) {
        unsigned long long bal = __ballot((pm.x + pm.y + pm.z + pm.w) > 0.0f);
        if (tid == 320) mflag[(t + 1) & 1] = (bal != 0ULL) ? 1.0f : 0.0f;
      }
    }
    barx();
  }
}

extern "C" void kernel_launch(void* const* d_in, const int* in_sizes, int n_in,
                              void* d_out, int out_size, void* d_ws, size_t ws_size,
                              hipStream_t stream) {
  const float* data = (const float*)d_in[0];
  const float* ts   = (const float*)d_in[1];
  const float* uw1  = (const float*)d_in[2];
  const float* ub1  = (const float*)d_in[3];
  const float* uw2  = (const float*)d_in[4];
  const float* ub2  = (const float*)d_in[5];
  const float* rw1  = (const float*)d_in[6];
  const float* rb1  = (const float*)d_in[7];
  const float* rw2  = (const float*)d_in[8];
  const float* rb2  = (const float*)d_in[9];
  const float* nw1  = (const float*)d_in[10];
  const float* nb1  = (const float*)d_in[11];
  const float* nw2  = (const float*)d_in[12];
  const float* nb2  = (const float*)d_in[13];

  rnn_fused<<<dim3(256), dim3(512), 0, stream>>>(
      data, ts, uw1, ub1, uw2, ub2, rw1, rb1, rw2, rb2, nw1, nb1, nw2, nb2,
      (float*)d_out);
}